// Round 1
// baseline (838.686 us; speedup 1.0000x reference)
//
#include <hip/hip_runtime.h>

#define DIM   128
#define N_REL 500
#define GAMMA 12.0f
#define EPS   1e-12f
#define SPLIT 2        // blocks per relation (index-range partition of the batch)
#define MAXS  96       // per-block sample capacity; lambda=8.2/block, P(>96) ~ 0

__device__ __forceinline__ float waveSum(float v) {
#pragma unroll
    for (int off = 32; off > 0; off >>= 1)
        v += __shfl_xor(v, off, 64);
    return v;
}

// Block (rel, sp): 128 threads, 2 waves. Thread e owns COLUMN e of M_rel in
// 128 VGPRs (coalesced column loads: lane-consecutive e -> 256B/instr).
// Matvec is a thread-local dot with x broadcast from LDS: no partial-sum LDS
// round-trip, 3 barriers per 2 samples (was 4). Entity rows for the next pair
// are prefetched into registers during the current pair's FMA phase.
// Entity pre-norm folded into projection norm (l2norm(l2norm(x)@M)==l2norm(x@M)).
// Reduction trees (chunk-16 dot accumulation, butterfly-64 + 2-half combine)
// replicate the previous kernel's order exactly.
__global__ __launch_bounds__(128, 2) void k_fused(
    const int* __restrict__ h, const int* __restrict__ r, const int* __restrict__ t,
    const float* __restrict__ ent_w, const float* __restrict__ rel_w,
    const float* __restrict__ mat_w, float* __restrict__ out, int B)
{
    const int rel  = blockIdx.x / SPLIT;
    const int sp   = blockIdx.x % SPLIT;
    const int e    = threadIdx.x;     // column owner / element index 0..127
    const int lane = e & 63;
    const int wv   = e >> 6;          // wave 0: e 0..63, wave 1: e 64..127

    // Issue matrix-column loads first; latency hides under the r-scan below.
    float Mc[DIM];
    const float* __restrict__ Mp = mat_w + (size_t)rel * DIM * DIM + e;
#pragma unroll
    for (int d = 0; d < DIM; ++d)
        Mc[d] = Mp[(size_t)d * DIM];

    __shared__ int    s_b[MAXS], s_h[MAXS], s_t[MAXS];
    __shared__ float  s_sg[MAXS];
    __shared__ int    lcnt;
    __shared__ float4 sx4[DIM];       // [d] = {h0,t0,h1,t1} raw entity elements
    __shared__ float  wsN[2][4];      // [wave][nh0,nt0,nh1,nt1] halves
    __shared__ float  wsD[2][2];      // [wave][dq0,dq1] halves
    __shared__ float  relh[2];        // rel-row norm^2 halves

    if (e == 0) lcnt = 0;
    __syncthreads();

    // ---- select my samples (disjoint index range), int4-vectorized scan
    const int lo = (B * sp) / SPLIT, hiEnd = (B * (sp + 1)) / SPLIT;
#pragma unroll 1
    for (int i = lo + e * 4; i < hiEnd; i += 128 * 4) {
        const int4 q = *(const int4*)(r + i);
        const int rr[4] = { q.x, q.y, q.z, q.w };
#pragma unroll
        for (int j = 0; j < 4; ++j) {
            const int ri = rr[j];
            const int mi = (ri >= N_REL) ? ri - N_REL : ri;
            if (mi == rel) {                 // ~8 matches per block total
                const int p = atomicAdd(&lcnt, 1);
                if (p < MAXS) {
                    s_b[p]  = i + j;
                    s_h[p]  = h[i + j];
                    s_t[p]  = t[i + j];
                    s_sg[p] = (ri >= N_REL) ? -1.0f : 1.0f;
                }
            }
        }
    }

    // ---- relation row: norm halves via butterfly, combine after barrier
    const float rvv = rel_w[(size_t)rel * DIM + e];
    {
        const float rp = waveSum(rvv * rvv);
        if (lane == 0) relh[wv] = rp;
    }
    __syncthreads();                  // lists + lcnt + relh visible
    const int n = min(lcnt, MAXS);
    if (n == 0) return;               // uniform exit
    const float srv_e = rvv / fmaxf(sqrtf(relh[0] + relh[1]), EPS);

    // ---- prologue prefetch: pair 0 entity rows into registers
    const int i1 = (1 < n) ? 1 : 0;
    float ph0 = ent_w[(size_t)s_h[0]  * DIM + e];
    float pt0 = ent_w[(size_t)s_t[0]  * DIM + e];
    float ph1 = ent_w[(size_t)s_h[i1] * DIM + e];
    float pt1 = ent_w[(size_t)s_t[i1] * DIM + e];

    // ---- main loop: 2 samples per iteration, 3 barriers
    for (int s0 = 0; s0 < n; s0 += 2) {
        const bool two = (s0 + 1 < n);

        // stage prefetched rows (last readers of sx4 were before previous B2;
        // we are past previous B3 -> safe)
        sx4[e] = make_float4(ph0, pt0, ph1, pt1);
        __syncthreads();              // B1: x visible

        // issue next-pair prefetch now; latency hides under the FMA phase
        if (s0 + 2 < n) {
            const int a = s0 + 2;
            const int b = (s0 + 3 < n) ? s0 + 3 : a;
            ph0 = ent_w[(size_t)s_h[a] * DIM + e];
            pt0 = ent_w[(size_t)s_t[a] * DIM + e];
            ph1 = ent_w[(size_t)s_h[b] * DIM + e];
            pt1 = ent_w[(size_t)s_t[b] * DIM + e];
        }

        // thread-local matvec: 4 vectors x my column, chunk-16 accumulation
        // (same fp tree as previous kernel's part[]-based reduction)
        float hp0 = 0.f, tp0 = 0.f, hp1 = 0.f, tp1 = 0.f;
#pragma unroll
        for (int k = 0; k < 8; ++k) {
            float c0 = 0.f, c1 = 0.f, c2 = 0.f, c3 = 0.f;
#pragma unroll
            for (int dd = 0; dd < 16; ++dd) {
                const float4 x = sx4[k * 16 + dd];   // LDS broadcast (b128)
                const float  m = Mc[k * 16 + dd];
                c0 += x.x * m;
                c1 += x.y * m;
                c2 += x.z * m;
                c3 += x.w * m;
            }
            hp0 += c0; tp0 += c1; hp1 += c2; tp1 += c3;
        }

        // projection norms: butterfly halves, combine after barrier
        const float nh0 = waveSum(hp0 * hp0);
        const float nt0 = waveSum(tp0 * tp0);
        const float nh1 = waveSum(hp1 * hp1);
        const float nt1 = waveSum(tp1 * tp1);
        if (lane == 0) {
            wsN[wv][0] = nh0; wsN[wv][1] = nt0;
            wsN[wv][2] = nh1; wsN[wv][3] = nt1;
        }
        __syncthreads();              // B2: norm halves visible

        const float hinv0 = 1.0f / fmaxf(sqrtf(wsN[0][0] + wsN[1][0]), EPS);
        const float tinv0 = 1.0f / fmaxf(sqrtf(wsN[0][1] + wsN[1][1]), EPS);
        const float hinv1 = 1.0f / fmaxf(sqrtf(wsN[0][2] + wsN[1][2]), EPS);
        const float tinv1 = 1.0f / fmaxf(sqrtf(wsN[0][3] + wsN[1][3]), EPS);
        const float sg0   = s_sg[s0];
        const float sg1   = s_sg[two ? s0 + 1 : s0];

        const float d0  = hp0 * hinv0 + sg0 * srv_e - tp0 * tinv0;
        const float d1  = hp1 * hinv1 + sg1 * srv_e - tp1 * tinv1;
        const float dq0 = waveSum(d0 * d0);
        const float dq1 = waveSum(d1 * d1);
        if (lane == 0) { wsD[wv][0] = dq0; wsD[wv][1] = dq1; }
        __syncthreads();              // B3: dq halves visible

        if (e == 0)        out[s_b[s0]]     = GAMMA - sqrtf(wsD[0][0] + wsD[1][0]);
        if (e == 1 && two) out[s_b[s0 + 1]] = GAMMA - sqrtf(wsD[0][1] + wsD[1][1]);
    }
}

extern "C" void kernel_launch(void* const* d_in, const int* in_sizes, int n_in,
                              void* d_out, int out_size, void* d_ws, size_t ws_size,
                              hipStream_t stream) {
    const int*   h     = (const int*)d_in[0];
    const int*   r     = (const int*)d_in[1];
    const int*   t     = (const int*)d_in[2];
    const float* ent_w = (const float*)d_in[3];
    const float* rel_w = (const float*)d_in[4];
    const float* mat_w = (const float*)d_in[5];
    float*       out   = (float*)d_out;
    const int B = in_sizes[0];   // 16384

    k_fused<<<N_REL * SPLIT, 128, 0, stream>>>(h, r, t, ent_w, rel_w, mat_w, out, B);
}

// Round 2
// 552.961 us; speedup vs baseline: 1.5167x; 1.5167x over previous
//
#include <hip/hip_runtime.h>

#define DIM   128
#define N_REL 500
#define GAMMA 12.0f
#define EPS   1e-12f
#define SPLIT 2        // blocks per relation (index-range partition of the batch)
#define MAXS  96       // per-block sample capacity; lambda=16.4, P(>96) ~ 0

__device__ __forceinline__ float waveSum(float v) {
#pragma unroll
    for (int off = 32; off > 0; off >>= 1)
        v += __shfl_xor(v, off, 64);
    return v;
}

// Block (rel, sp): 128 threads, 2 waves. Thread e owns COLUMN e of M_rel in
// 128 VGPRs (coalesced column loads: lane-consecutive e -> 256B/instr).
// Matvec is a thread-local dot with x broadcast from LDS: no partial-sum LDS
// round-trip, 3 barriers per 2 samples. Entity rows for the next pair are
// prefetched into registers during the current pair's FMA phase.
//
// ROUND-2 FIX: round 1 spilled Mc[] to scratch (VGPR_Count=128, FETCH 565MB of
// scratch re-reads). __launch_bounds__(128,1) gives the full 512-VGPR budget
// and all Mc indices are forced compile-time constant via explicit unroll
// counts so SROA promotes the array to registers.
//
// Entity pre-norm folded into projection norm (l2norm(l2norm(x)@M)==l2norm(x@M)).
// Reduction trees (chunk-16 dot accumulation, butterfly-64 + 2-half combine)
// are unchanged from the previously-passing kernels (absmax was 0.0).
__global__ __launch_bounds__(128, 1) void k_fused(
    const int* __restrict__ h, const int* __restrict__ r, const int* __restrict__ t,
    const float* __restrict__ ent_w, const float* __restrict__ rel_w,
    const float* __restrict__ mat_w, float* __restrict__ out, int B)
{
    const int rel  = blockIdx.x / SPLIT;
    const int sp   = blockIdx.x % SPLIT;
    const int e    = threadIdx.x;     // column owner / element index 0..127
    const int lane = e & 63;
    const int wv   = e >> 6;          // wave 0: e 0..63, wave 1: e 64..127

    // Issue matrix-column loads first; latency hides under the r-scan below.
    // Constant-index unroll -> Mc lives in VGPRs (128 of them).
    float Mc[DIM];
    const float* __restrict__ Mp = mat_w + (size_t)rel * (DIM * DIM) + e;
#pragma unroll 128
    for (int d = 0; d < DIM; ++d)
        Mc[d] = Mp[d * DIM];

    __shared__ int    s_b[MAXS], s_h[MAXS], s_t[MAXS];
    __shared__ float  s_sg[MAXS];
    __shared__ int    lcnt;
    __shared__ float4 sx4[DIM];       // [d] = {h0,t0,h1,t1} raw entity elements
    __shared__ float  wsN[2][4];      // [wave][nh0,nt0,nh1,nt1] halves
    __shared__ float  wsD[2][2];      // [wave][dq0,dq1] halves
    __shared__ float  relh[2];        // rel-row norm^2 halves

    if (e == 0) lcnt = 0;
    __syncthreads();

    // ---- select my samples (disjoint index range), int4-vectorized scan
    const int lo = (B * sp) / SPLIT, hiEnd = (B * (sp + 1)) / SPLIT;
#pragma unroll 1
    for (int i = lo + e * 4; i < hiEnd; i += 128 * 4) {
        const int4 q = *(const int4*)(r + i);
        const int rr[4] = { q.x, q.y, q.z, q.w };
#pragma unroll
        for (int j = 0; j < 4; ++j) {
            const int ri = rr[j];
            const int mi = (ri >= N_REL) ? ri - N_REL : ri;
            if (mi == rel) {                 // ~16 matches per block total
                const int p = atomicAdd(&lcnt, 1);
                if (p < MAXS) {
                    s_b[p]  = i + j;
                    s_h[p]  = h[i + j];
                    s_t[p]  = t[i + j];
                    s_sg[p] = (ri >= N_REL) ? -1.0f : 1.0f;
                }
            }
        }
    }

    // ---- relation row: norm halves via butterfly, combine after barrier
    const float rvv = rel_w[(size_t)rel * DIM + e];
    {
        const float rp = waveSum(rvv * rvv);
        if (lane == 0) relh[wv] = rp;
    }
    __syncthreads();                  // lists + lcnt + relh visible
    const int n = min(lcnt, MAXS);
    if (n == 0) return;               // uniform exit
    const float srv_e = rvv / fmaxf(sqrtf(relh[0] + relh[1]), EPS);

    // ---- prologue prefetch: pair 0 entity rows into registers
    const int i1 = (1 < n) ? 1 : 0;
    float ph0 = ent_w[(size_t)s_h[0]  * DIM + e];
    float pt0 = ent_w[(size_t)s_t[0]  * DIM + e];
    float ph1 = ent_w[(size_t)s_h[i1] * DIM + e];
    float pt1 = ent_w[(size_t)s_t[i1] * DIM + e];

    // ---- main loop: 2 samples per iteration, 3 barriers
    for (int s0 = 0; s0 < n; s0 += 2) {
        const bool two = (s0 + 1 < n);

        // stage prefetched rows (last readers of sx4 were before previous B2;
        // we are past previous B3 -> safe)
        sx4[e] = make_float4(ph0, pt0, ph1, pt1);
        __syncthreads();              // B1: x visible

        // issue next-pair prefetch now; latency hides under the FMA phase
        if (s0 + 2 < n) {
            const int a = s0 + 2;
            const int b = (s0 + 3 < n) ? s0 + 3 : a;
            ph0 = ent_w[(size_t)s_h[a] * DIM + e];
            pt0 = ent_w[(size_t)s_t[a] * DIM + e];
            ph1 = ent_w[(size_t)s_h[b] * DIM + e];
            pt1 = ent_w[(size_t)s_t[b] * DIM + e];
        }

        // thread-local matvec: 4 vectors x my column, chunk-16 accumulation
        // (same fp tree as the previously-passing kernels)
        float hp0 = 0.f, tp0 = 0.f, hp1 = 0.f, tp1 = 0.f;
#pragma unroll 8
        for (int k = 0; k < 8; ++k) {
            float c0 = 0.f, c1 = 0.f, c2 = 0.f, c3 = 0.f;
#pragma unroll 16
            for (int dd = 0; dd < 16; ++dd) {
                const float4 x = sx4[k * 16 + dd];   // LDS broadcast (b128)
                const float  m = Mc[k * 16 + dd];
                c0 += x.x * m;
                c1 += x.y * m;
                c2 += x.z * m;
                c3 += x.w * m;
            }
            hp0 += c0; tp0 += c1; hp1 += c2; tp1 += c3;
        }

        // projection norms: butterfly halves, combine after barrier
        const float nh0 = waveSum(hp0 * hp0);
        const float nt0 = waveSum(tp0 * tp0);
        const float nh1 = waveSum(hp1 * hp1);
        const float nt1 = waveSum(tp1 * tp1);
        if (lane == 0) {
            wsN[wv][0] = nh0; wsN[wv][1] = nt0;
            wsN[wv][2] = nh1; wsN[wv][3] = nt1;
        }
        __syncthreads();              // B2: norm halves visible

        const float hinv0 = 1.0f / fmaxf(sqrtf(wsN[0][0] + wsN[1][0]), EPS);
        const float tinv0 = 1.0f / fmaxf(sqrtf(wsN[0][1] + wsN[1][1]), EPS);
        const float hinv1 = 1.0f / fmaxf(sqrtf(wsN[0][2] + wsN[1][2]), EPS);
        const float tinv1 = 1.0f / fmaxf(sqrtf(wsN[0][3] + wsN[1][3]), EPS);
        const float sg0   = s_sg[s0];
        const float sg1   = s_sg[two ? s0 + 1 : s0];

        const float d0  = hp0 * hinv0 + sg0 * srv_e - tp0 * tinv0;
        const float d1  = hp1 * hinv1 + sg1 * srv_e - tp1 * tinv1;
        const float dq0 = waveSum(d0 * d0);
        const float dq1 = waveSum(d1 * d1);
        if (lane == 0) { wsD[wv][0] = dq0; wsD[wv][1] = dq1; }
        __syncthreads();              // B3: dq halves visible

        if (e == 0)        out[s_b[s0]]     = GAMMA - sqrtf(wsD[0][0] + wsD[1][0]);
        if (e == 1 && two) out[s_b[s0 + 1]] = GAMMA - sqrtf(wsD[0][1] + wsD[1][1]);
    }
}

extern "C" void kernel_launch(void* const* d_in, const int* in_sizes, int n_in,
                              void* d_out, int out_size, void* d_ws, size_t ws_size,
                              hipStream_t stream) {
    const int*   h     = (const int*)d_in[0];
    const int*   r     = (const int*)d_in[1];
    const int*   t     = (const int*)d_in[2];
    const float* ent_w = (const float*)d_in[3];
    const float* rel_w = (const float*)d_in[4];
    const float* mat_w = (const float*)d_in[5];
    float*       out   = (float*)d_out;
    const int B = in_sizes[0];   // 16384

    k_fused<<<N_REL * SPLIT, 128, 0, stream>>>(h, r, t, ent_w, rel_w, mat_w, out, B);
}

// Round 3
// 491.748 us; speedup vs baseline: 1.7055x; 1.1245x over previous
//
#include <hip/hip_runtime.h>

#define DIM   128
#define N_REL 500
#define GAMMA 12.0f
#define EPS   1e-12f
#define SPLIT 2        // blocks per relation (index-range partition of the batch)
#define MAXS  96       // per-block capacity; lambda=16.4/block, P(>96) ~ 0

__device__ __forceinline__ float waveSum(float v) {
#pragma unroll
    for (int off = 32; off > 0; off >>= 1)
        v += __shfl_xor(v, off, 64);
    return v;
}

// Block (rel, sp): 256 threads, 4 waves. Thread (g = tid>>7, e = tid&127) owns
// ROWS g*64..g*64+63 of COLUMN e of M_rel in 64 VGPRs. Matvec is thread-local
// over the half-column; the two halves combine via a tiny per-chunk LDS
// exchange that preserves the exact sequential chunk-summation tree
// (((ch0+ch1)+ch2)+...)+ch7 of all previously-passing kernels (absmax 0.0).
//
// ROUND-3 FIX: round 2's Mc[128] landed at 248 VGPRs — at the 256 cliff with
// ~8 spare regs, the compiler couldn't pipeline ds_reads or keep entity
// prefetches in flight (266 us, VALUBusy 11%, fetch trickle). Half the M
// footprint (~105 peak regs under a 128 cap) restores pipelining headroom and
// doubles residency to 16 waves/CU (4 blocks/CU -> one dispatch round).
__global__ __launch_bounds__(256, 4) void k_fused(
    const int* __restrict__ h, const int* __restrict__ r, const int* __restrict__ t,
    const float* __restrict__ ent_w, const float* __restrict__ rel_w,
    const float* __restrict__ mat_w, float* __restrict__ out, int B)
{
    const int rel  = blockIdx.x / SPLIT;
    const int sp   = blockIdx.x % SPLIT;
    const int tid  = threadIdx.x;
    const int e    = tid & 127;    // column owner
    const int g    = tid >> 7;     // row-half: rows g*64 .. g*64+63
    const int lane = tid & 63;
    const int wv   = tid >> 6;     // wave 0..3 (waves 0,1 = group 0)

    // Half-column of M into 64 VGPRs. Per-wave coalesced (lane-consecutive e,
    // 256B/instr); latency hides under the r-scan below.
    float Mc[64];
    const float* __restrict__ Mp =
        mat_w + (size_t)rel * (DIM * DIM) + (size_t)(g * 64) * DIM + e;
#pragma unroll 64
    for (int d = 0; d < 64; ++d)
        Mc[d] = Mp[d * DIM];

    __shared__ int    s_b[MAXS], s_h[MAXS], s_t[MAXS];
    __shared__ float  s_sg[MAXS];
    __shared__ int    lcnt;
    __shared__ float2 sxA[DIM];         // [d] = (h0[d], t0[d])
    __shared__ float2 sxB[DIM];         // [d] = (h1[d], t1[d])
    __shared__ float  part[4][4][DIM];  // [vec][chunk 4..7][e] from group 1
    __shared__ float  wsN[2][4];        // [wave][nh0,nt0,nh1,nt1] halves
    __shared__ float  wsD[2][2];        // [wave][dq0,dq1] halves
    __shared__ float  relh[2];          // rel-row norm^2 halves

    if (tid == 0) lcnt = 0;
    __syncthreads();

    // ---- select my samples (disjoint index range), int4-vectorized scan
    const int lo = (B * sp) / SPLIT, hiEnd = (B * (sp + 1)) / SPLIT;
#pragma unroll 1
    for (int i = lo + tid * 4; i < hiEnd; i += 256 * 4) {
        const int4 q = *(const int4*)(r + i);
        const int rr[4] = { q.x, q.y, q.z, q.w };
#pragma unroll
        for (int j = 0; j < 4; ++j) {
            const int ri = rr[j];
            const int mi = (ri >= N_REL) ? ri - N_REL : ri;
            if (mi == rel) {                 // ~16 matches per block total
                const int p = atomicAdd(&lcnt, 1);
                if (p < MAXS) {
                    s_b[p]  = i + j;
                    s_h[p]  = h[i + j];
                    s_t[p]  = t[i + j];
                    s_sg[p] = (ri >= N_REL) ? -1.0f : 1.0f;
                }
            }
        }
    }

    // ---- relation row: group 0 only; butterfly + 2-half combine (same tree)
    float rvv = 0.0f;
    if (tid < 128) {
        rvv = rel_w[(size_t)rel * DIM + e];
        const float rp = waveSum(rvv * rvv);
        if (lane == 0) relh[wv] = rp;
    }
    __syncthreads();                  // lists + lcnt + relh visible
    const int n = min(lcnt, MAXS);
    if (n == 0) return;               // uniform exit
    const float srv_e = rvv / fmaxf(sqrtf(relh[0] + relh[1]), EPS); // tid<128 only

    // ---- prologue prefetch: group g fetches rows of sample (s0+g)
    {
        const int j1  = (1 < n) ? 1 : 0;
        const int myi = g ? j1 : 0;
        // fall through to loop-top staging
        float pa = ent_w[(size_t)s_h[myi] * DIM + e];
        float pb = ent_w[(size_t)s_t[myi] * DIM + e];

        // ---- main loop: 2 samples per iteration
        for (int s0 = 0; s0 < n; s0 += 2) {
            const bool two = (s0 + 1 < n);

            // stage prefetched rows (last sx reads were before previous B2;
            // we are past previous B4 -> safe)
            if (g == 0) sxA[e] = make_float2(pa, pb);
            else        sxB[e] = make_float2(pa, pb);
            __syncthreads();          // B1: x visible

            // issue next-pair prefetch; latency hides under FMA + reductions
            if (s0 + 2 < n) {
                const int ii = (s0 + 2 + g < n) ? s0 + 2 + g : s0 + 2;
                pa = ent_w[(size_t)s_h[ii] * DIM + e];
                pb = ent_w[(size_t)s_t[ii] * DIM + e];
            }

            // thread-local half-column matvec, chunk-16 accumulation.
            // group 0 sums chunks 0..3 sequentially; group 1 exports its four
            // chunk values per vector so group 0 can extend the SAME tree.
            float hp0 = 0.f, tp0 = 0.f, hp1 = 0.f, tp1 = 0.f;
#pragma unroll
            for (int k = 0; k < 4; ++k) {
                float c0 = 0.f, c1 = 0.f, c2 = 0.f, c3 = 0.f;
#pragma unroll
                for (int dd = 0; dd < 16; ++dd) {
                    const int d = g * 64 + k * 16 + dd;
                    const float2 u = sxA[d];     // LDS broadcast
                    const float2 w = sxB[d];     // LDS broadcast
                    const float  m = Mc[k * 16 + dd];
                    c0 += u.x * m;
                    c1 += u.y * m;
                    c2 += w.x * m;
                    c3 += w.y * m;
                }
                if (g == 0) { hp0 += c0; tp0 += c1; hp1 += c2; tp1 += c3; }
                else {
                    part[0][k][e] = c0;          // lane-consecutive: conflict-free
                    part[1][k][e] = c1;
                    part[2][k][e] = c2;
                    part[3][k][e] = c3;
                }
            }
            __syncthreads();          // B2: partials visible

            if (tid < 128) {
                // extend the chunk chain: += ch4, ch5, ch6, ch7 in order
#pragma unroll
                for (int k = 0; k < 4; ++k) {
                    hp0 += part[0][k][e];
                    tp0 += part[1][k][e];
                    hp1 += part[2][k][e];
                    tp1 += part[3][k][e];
                }
                const float nh0 = waveSum(hp0 * hp0);
                const float nt0 = waveSum(tp0 * tp0);
                const float nh1 = waveSum(hp1 * hp1);
                const float nt1 = waveSum(tp1 * tp1);
                if (lane == 0) {
                    wsN[wv][0] = nh0; wsN[wv][1] = nt0;
                    wsN[wv][2] = nh1; wsN[wv][3] = nt1;
                }
            }
            __syncthreads();          // B3: norm halves visible

            if (tid < 128) {
                const float hinv0 = 1.0f / fmaxf(sqrtf(wsN[0][0] + wsN[1][0]), EPS);
                const float tinv0 = 1.0f / fmaxf(sqrtf(wsN[0][1] + wsN[1][1]), EPS);
                const float hinv1 = 1.0f / fmaxf(sqrtf(wsN[0][2] + wsN[1][2]), EPS);
                const float tinv1 = 1.0f / fmaxf(sqrtf(wsN[0][3] + wsN[1][3]), EPS);
                const float sg0   = s_sg[s0];
                const float sg1   = s_sg[two ? s0 + 1 : s0];

                const float d0  = hp0 * hinv0 + sg0 * srv_e - tp0 * tinv0;
                const float d1  = hp1 * hinv1 + sg1 * srv_e - tp1 * tinv1;
                const float dq0 = waveSum(d0 * d0);
                const float dq1 = waveSum(d1 * d1);
                if (lane == 0) { wsD[wv][0] = dq0; wsD[wv][1] = dq1; }
            }
            __syncthreads();          // B4: dq halves visible

            if (tid == 0)        out[s_b[s0]]     = GAMMA - sqrtf(wsD[0][0] + wsD[1][0]);
            if (tid == 1 && two) out[s_b[s0 + 1]] = GAMMA - sqrtf(wsD[0][1] + wsD[1][1]);
        }
    }
}

extern "C" void kernel_launch(void* const* d_in, const int* in_sizes, int n_in,
                              void* d_out, int out_size, void* d_ws, size_t ws_size,
                              hipStream_t stream) {
    const int*   h     = (const int*)d_in[0];
    const int*   r     = (const int*)d_in[1];
    const int*   t     = (const int*)d_in[2];
    const float* ent_w = (const float*)d_in[3];
    const float* rel_w = (const float*)d_in[4];
    const float* mat_w = (const float*)d_in[5];
    float*       out   = (float*)d_out;
    const int B = in_sizes[0];   // 16384

    k_fused<<<N_REL * SPLIT, 256, 0, stream>>>(h, r, t, ent_w, rel_w, mat_w, out, B);
}

// Round 4
// 349.653 us; speedup vs baseline: 2.3986x; 1.4064x over previous
//
#include <hip/hip_runtime.h>

#define DIM   128
#define N_REL 500
#define GAMMA 12.0f
#define EPS   1e-12f
#define SPLIT 2        // blocks per relation (index-range partition of the batch)
#define MAXS  96       // per-block capacity; lambda=16.4/block, P(>96) ~ 0

__device__ __forceinline__ float waveSum(float v) {
#pragma unroll
    for (int off = 32; off > 0; off >>= 1)
        v += __shfl_xor(v, off, 64);
    return v;
}

// ROUND-4: round 0's proven-no-spill structure (float4 Mreg[16]: 4 cols x 16
// rows per thread, LDS partial exchange, 4 barriers / 2 samples) + the two
// fixes identified in rounds 2-3:
//   (a) software-pipelined entity prefetch -- next pair's rows issue right
//       after B1 and stage at the next loop top, hiding the ~900cy random-row
//       miss that round 0 paid serially every iteration;
//   (b) int4-vectorized r-scan (32 -> 8 scan iterations).
// Float arrays as plain float[64] spilled under the (256,4) cap in rounds 1/3;
// the float4[16] encoding is the allocator-proven form. All FMA/reduction
// trees are bit-identical to round 0 (absmax 0.0).
__global__ __launch_bounds__(256, 4) void k_fused(
    const int* __restrict__ h, const int* __restrict__ r, const int* __restrict__ t,
    const float* __restrict__ ent_w, const float* __restrict__ rel_w,
    const float* __restrict__ mat_w, float* __restrict__ out, int B)
{
    const int rel  = blockIdx.x / SPLIT;
    const int sp   = blockIdx.x % SPLIT;
    const int tid  = threadIdx.x;
    const int eg   = tid & 31;   // column group: cols 4eg..4eg+3
    const int dc   = tid >> 5;   // d-chunk 0..7 (rows dc*16..dc*16+15)
    const int e    = tid & 127;  // element index
    const int vsel = tid >> 7;   // 0: h-side, 1: t-side
    const int lane = tid & 63;
    const int wv   = tid >> 6;   // wave 0..3

    // Matrix tile into registers first; waitcnt lands before first FMA,
    // latency hides under the r-scan below.
    const float4* __restrict__ M4 = (const float4*)(mat_w + (size_t)rel * DIM * DIM);
    float4 Mreg[16];
#pragma unroll
    for (int dd = 0; dd < 16; ++dd)
        Mreg[dd] = M4[(dc * 16 + dd) * 32 + eg];

    __shared__ int   s_b[MAXS], s_h[MAXS], s_t[MAXS];
    __shared__ float s_sg[MAXS];
    __shared__ int   lcnt;
    __shared__ float srv[DIM];          // l2norm(rel row), unsigned
    __shared__ float sv[4][DIM];        // h0, t0, h1, t1 raw entity rows
    __shared__ float part[8][4][DIM];   // [dc][vec][e] matvec partials
    __shared__ float ppv[4][DIM];       // raw projections hp0,tp0,hp1,tp1
    __shared__ float wsA[4], wsB[4], wsD[4];

    if (tid == 0) lcnt = 0;
    __syncthreads();

    // ---- select my samples (disjoint index range). int4 scan when aligned.
    const int lo = (B * sp) / SPLIT, hiEnd = (B * (sp + 1)) / SPLIT;
    if ((lo & 3) == 0) {
        const int span   = hiEnd - lo;
        const int vecEnd = lo + (span & ~3);
#pragma unroll 1
        for (int i = lo + tid * 4; i < vecEnd; i += 256 * 4) {
            const int4 q = *(const int4*)(r + i);
            const int rr[4] = { q.x, q.y, q.z, q.w };
#pragma unroll
            for (int j = 0; j < 4; ++j) {
                const int ri = rr[j];
                const int mi = (ri >= N_REL) ? ri - N_REL : ri;
                if (mi == rel) {
                    const int p = atomicAdd(&lcnt, 1);
                    if (p < MAXS) {
                        s_b[p]  = i + j;
                        s_h[p]  = h[i + j];
                        s_t[p]  = t[i + j];
                        s_sg[p] = (ri >= N_REL) ? -1.0f : 1.0f;
                    }
                }
            }
        }
#pragma unroll 1
        for (int i = vecEnd + tid; i < hiEnd; i += 256) {
            const int ri = r[i];
            const int mi = (ri >= N_REL) ? ri - N_REL : ri;
            if (mi == rel) {
                const int p = atomicAdd(&lcnt, 1);
                if (p < MAXS) {
                    s_b[p] = i; s_h[p] = h[i]; s_t[p] = t[i];
                    s_sg[p] = (ri >= N_REL) ? -1.0f : 1.0f;
                }
            }
        }
    } else {
#pragma unroll 1
        for (int i = lo + tid; i < hiEnd; i += 256) {
            const int ri = r[i];
            const int mi = (ri >= N_REL) ? ri - N_REL : ri;
            if (mi == rel) {
                const int p = atomicAdd(&lcnt, 1);
                if (p < MAXS) {
                    s_b[p] = i; s_h[p] = h[i]; s_t[p] = t[i];
                    s_sg[p] = (ri >= N_REL) ? -1.0f : 1.0f;
                }
            }
        }
    }

    // ---- normalized relation row (once per block) -- round 0 verbatim
    float rv = (vsel == 0) ? rel_w[(size_t)rel * DIM + e] : 0.0f;
    float rp = waveSum(rv * rv);
    if (lane == 0) wsA[wv] = rp;
    __syncthreads();                      // lcnt + lists + wsA visible
    const int n = min(lcnt, MAXS);
    if (n == 0) return;                   // uniform exit
    if (vsel == 0)
        srv[e] = rv / fmaxf(sqrtf(wsA[0] + wsA[1]), EPS);
    __syncthreads();                      // srv visible; wsA free for reuse

    // ---- prologue prefetch: this thread feeds vec (2j+vsel) element e
    const int j1 = (1 < n) ? 1 : 0;
    float p0 = ent_w[(size_t)(vsel ? s_t[0]  : s_h[0])  * DIM + e];
    float p1 = ent_w[(size_t)(vsel ? s_t[j1] : s_h[j1]) * DIM + e];

    // ---- main loop: 2 samples (4 vectors) per iteration
    for (int s0 = 0; s0 < n; s0 += 2) {
        const bool two = (s0 + 1 < n);

        // stage prefetched rows (last sv readers were before previous B2;
        // we are past previous B4 -> safe)
        sv[vsel][e]     = p0;
        sv[2 + vsel][e] = p1;
        __syncthreads();                  // B1

        // issue next-pair prefetch; latency hides under the FMA + reductions
        if (s0 + 2 < n) {
            const int a = s0 + 2;
            const int b = (s0 + 3 < n) ? s0 + 3 : a;
            p0 = ent_w[(size_t)(vsel ? s_t[a] : s_h[a]) * DIM + e];
            p1 = ent_w[(size_t)(vsel ? s_t[b] : s_h[b]) * DIM + e];
        }

        // matvec partials: 4 vectors x register matrix (round 0 verbatim)
        float4 a0 = make_float4(0.f,0.f,0.f,0.f), a1 = a0, a2 = a0, a3 = a0;
#pragma unroll
        for (int dd = 0; dd < 16; ++dd) {
            const float4 m = Mreg[dd];
            const float x0 = sv[0][dc*16+dd], x1 = sv[1][dc*16+dd];
            const float x2 = sv[2][dc*16+dd], x3 = sv[3][dc*16+dd];
            a0.x += x0*m.x; a0.y += x0*m.y; a0.z += x0*m.z; a0.w += x0*m.w;
            a1.x += x1*m.x; a1.y += x1*m.y; a1.z += x1*m.z; a1.w += x1*m.w;
            a2.x += x2*m.x; a2.y += x2*m.y; a2.z += x2*m.z; a2.w += x2*m.w;
            a3.x += x3*m.x; a3.y += x3*m.y; a3.z += x3*m.z; a3.w += x3*m.w;
        }
        *(float4*)&part[dc][0][4*eg] = a0;
        *(float4*)&part[dc][1][4*eg] = a1;
        *(float4*)&part[dc][2][4*eg] = a2;
        *(float4*)&part[dc][3][4*eg] = a3;
        __syncthreads();                  // B2

        // reduce 8 d-chunks; this thread covers vectors vsel and vsel+2 at e
        float v0 = 0.f, v1 = 0.f;
#pragma unroll
        for (int k = 0; k < 8; ++k) {
            v0 += part[k][vsel][e];
            v1 += part[k][vsel + 2][e];
        }
        ppv[vsel][e]     = v0;            // hp0 / tp0
        ppv[vsel + 2][e] = v1;            // hp1 / tp1
        const float n0 = waveSum(v0 * v0);
        const float n1 = waveSum(v1 * v1);
        if (lane == 0) { wsA[wv] = n0; wsB[wv] = n1; }
        __syncthreads();                  // B3

        // distance: waves 0,1 do sample0; waves 2,3 do sample1
        const int   smp  = wv >> 1;
        const float hs   = smp ? (wsB[0] + wsB[1]) : (wsA[0] + wsA[1]);
        const float ts   = smp ? (wsB[2] + wsB[3]) : (wsA[2] + wsA[3]);
        const float hinv = 1.0f / fmaxf(sqrtf(hs), EPS);
        const float tinv = 1.0f / fmaxf(sqrtf(ts), EPS);
        const float sg   = s_sg[s0 + smp < n ? s0 + smp : s0];
        const float d    = ppv[2*smp][e] * hinv + sg * srv[e] - ppv[2*smp+1][e] * tinv;
        const float dq   = waveSum(d * d);
        if (lane == 0) wsD[wv] = dq;
        __syncthreads();                  // B4

        if (tid == 0)        out[s_b[s0]]     = GAMMA - sqrtf(wsD[0] + wsD[1]);
        if (tid == 1 && two) out[s_b[s0 + 1]] = GAMMA - sqrtf(wsD[2] + wsD[3]);
    }
}

extern "C" void kernel_launch(void* const* d_in, const int* in_sizes, int n_in,
                              void* d_out, int out_size, void* d_ws, size_t ws_size,
                              hipStream_t stream) {
    const int*   h     = (const int*)d_in[0];
    const int*   r     = (const int*)d_in[1];
    const int*   t     = (const int*)d_in[2];
    const float* ent_w = (const float*)d_in[3];
    const float* rel_w = (const float*)d_in[4];
    const float* mat_w = (const float*)d_in[5];
    float*       out   = (float*)d_out;
    const int B = in_sizes[0];   // 16384

    k_fused<<<N_REL * SPLIT, 256, 0, stream>>>(h, r, t, ent_w, rel_w, mat_w, out, B);
}